// Round 5
// baseline (452.073 us; speedup 1.0000x reference)
//
#include <hip/hip_runtime.h>
#include <math.h>

#define N_PIX 1024
#define NV 64
#define NT 16                 // tiles per axis (1024/64)
#define TILE 64
#define HALO 70               // TILE + 6 (7x7 conv halo)
#define CAP 320               // entries per bin; mean occupancy ~117 (uniform points)
#define NBINS (NV * NT * NT)  // 16384
#define CUBE_ELEMS (NV * N_PIX * N_PIX)
#define RS 76                 // raw LDS row stride: 4*RS = 304 ≡ 16 mod 32 banks
                              // -> wave row-groups (q0=0,4,8,12) hit 2-way max (free)

typedef float f32x4 __attribute__((ext_vector_type(4)));  // nontemporal-store-able

// ---------------- pass A: bin points into (channel, tile) buckets ----------------
// Index math bit-matches the XLA-jitted reference (verified): x/y via
// (c+51.15f)*10.0f, v via true fp32 division. The reference drops only on the
// FLAT index, so negative ix0/iy0 wrap into neighboring rows/channels —
// reproduced exactly by unflattening idx back to (iv,iy,ix).
// A point is replicated into every tile whose 70x70 halo window contains its
// voxel (up to 4 bins).
__global__ __launch_bounds__(256) void splat_bin(
    const float2* __restrict__ pos,
    const float*  __restrict__ vel_chan,
    const float*  __restrict__ flux,
    const float*  __restrict__ vel_axis,
    unsigned*     __restrict__ cnt,
    uint2*        __restrict__ entries, int M)
{
    int i = blockIdx.x * 256 + threadIdx.x;
    if (i >= M) return;

    const float FOV_HALF = 51.15f;
    const float INV_PIX  = 10.0f;
    const float vel0 = vel_axis[0];
    const float dv   = vel_axis[1] - vel0;

    float2 p = pos[i];
    float  v = vel_chan[i];
    float  f = flux[i];

    int ix0 = (int)floorf((p.x + FOV_HALF) * INV_PIX);
    int iy0 = (int)floorf((p.y + FOV_HALF) * INV_PIX);
    int iv0 = (int)floorf((v - vel0) / dv);

    const int margin = 4;
    if (!(ix0 >= -margin && ix0 < N_PIX + margin &&
          iy0 >= -margin && iy0 < N_PIX + margin &&
          iv0 >= 0 && iv0 < NV)) return;

    int idx = (iv0 * N_PIX + iy0) * N_PIX + ix0;   // may be negative / OOB
    if (idx < 0 || idx >= CUBE_ELEMS) return;       // reference mode="drop"
    int iv = idx >> 20;
    int iy = (idx >> 10) & 1023;
    int ix = idx & 1023;

    int tx = ix >> 6, ty = iy >> 6;
    int fx = ix & 63, fy = iy & 63;

    #pragma unroll
    for (int dy = -1; dy <= 1; ++dy) {
        if (dy < 0 && (fy >= 3 || ty == 0)) continue;      // halo of tile above
        if (dy > 0 && (fy < 61 || ty == NT - 1)) continue; // halo of tile below
        int ly  = fy + 3 - 64 * dy;                        // 0..69 within halo tile
        int byb = (iv * NT + (ty + dy)) * NT;
        #pragma unroll
        for (int dx = -1; dx <= 1; ++dx) {
            if (dx < 0 && (fx >= 3 || tx == 0)) continue;
            if (dx > 0 && (fx < 61 || tx == NT - 1)) continue;
            int lx  = fx + 3 - 64 * dx;
            int bin = byb + tx + dx;
            unsigned pos_ = atomicAdd(&cnt[bin], 1u);
            if (pos_ < CAP)
                entries[(size_t)bin * CAP + pos_] =
                    make_uint2((unsigned)((ly << 7) | lx), __float_as_uint(f));
        }
    }
}

// ---------------- pass B: per-tile LDS rasterize + fused separable 7x7 ----------------
// One block per (tile, channel). Splat entries into a 70-row LDS halo tile
// (LDS atomics), then each thread h-filters its 10 needed rows into registers
// (3 aligned ds_read_b128 per row) and does the 7-tap vertical reduction
// directly — no hb buffer, one fewer barrier, 21.3 KB LDS -> 7 blocks/CU
// (vs 4 with the separate hb buffer), so stores overlap across more blocks.
__global__ __launch_bounds__(256) void conv_tile(
    const unsigned* __restrict__ cnt,
    const uint2*    __restrict__ entries,
    const float*    __restrict__ k2d,
    float*          __restrict__ out)
{
    __shared__ float raw[HALO * RS];  // 70x76 floats = 21280 B

    const int t   = threadIdx.x;
    const int ch  = blockIdx.y;
    const int bin = ch * (NT * NT) + blockIdx.x;   // blockIdx.x = ty*16+tx

    // Recover 1-D kernel from row 3 of k2d: k2d[3][j] = g3*g[j], k2d[3][3]=g3^2.
    float g[7];
    {
        float g3 = sqrtf(k2d[24]);
        #pragma unroll
        for (int j = 0; j < 7; ++j) g[j] = k2d[21 + j] / g3;
    }

    // zero the raw halo tile (5320 floats = 1330 float4)
    for (int i4 = t; i4 < HALO * RS / 4; i4 += 256)
        ((float4*)raw)[i4] = make_float4(0.f, 0.f, 0.f, 0.f);
    __syncthreads();

    // splat this bin's entries (LDS atomics; ~117 entries avg per block)
    unsigned n = cnt[bin];
    if (n > CAP) n = CAP;
    const uint2* e = entries + (size_t)bin * CAP;
    for (unsigned i = t; i < n; i += 256) {
        uint2 u = e[i];
        atomicAdd(&raw[(u.x >> 7) * RS + (u.x & 127)], __uint_as_float(u.y));
    }
    __syncthreads();

    // fused h+v: thread owns 4 cols (xg..xg+3) x 4 output rows (q0..q0+3).
    // Output row R needs h-filtered rows R..R+6, i.e. raw rows q0..q0+9.
    // h at col c (padded p=c+3) needs raw p in [c, c+6]; for c in [xg,xg+3]
    // that's p in [xg, xg+9], covered by aligned b128 reads at xg, xg+4, xg+8
    // (reads up to p=71 < RS; p=70,71 are zero / unused taps).
    const int xg = (t & 15) << 2;
    const int q0 = (t >> 4) << 2;

    float4 h[10];
    #pragma unroll
    for (int j = 0; j < 10; ++j) {
        const float* rp = &raw[(q0 + j) * RS + xg];
        float4 a = *(const float4*)(rp);
        float4 b = *(const float4*)(rp + 4);
        float4 c = *(const float4*)(rp + 8);
        float rr[12] = {a.x, a.y, a.z, a.w, b.x, b.y, b.z, b.w, c.x, c.y, c.z, c.w};
        float s0 = 0.f, s1 = 0.f, s2 = 0.f, s3 = 0.f;
        #pragma unroll
        for (int jj = 0; jj < 7; ++jj) {
            s0 = fmaf(rr[jj],     g[jj], s0);
            s1 = fmaf(rr[jj + 1], g[jj], s1);
            s2 = fmaf(rr[jj + 2], g[jj], s2);
            s3 = fmaf(rr[jj + 3], g[jj], s3);
        }
        h[j] = make_float4(s0, s1, s2, s3);
    }

    const int ty = blockIdx.x >> 4, tx = blockIdx.x & 15;
    float* __restrict__ dst = out + ((size_t)ch << 20)
                            + ((size_t)(ty * TILE + q0) << 10) + tx * TILE + xg;
    #pragma unroll
    for (int i = 0; i < 4; ++i) {
        float4 acc = make_float4(0.f, 0.f, 0.f, 0.f);
        #pragma unroll
        for (int k = 0; k < 7; ++k) {
            acc.x = fmaf(h[i + k].x, g[k], acc.x);
            acc.y = fmaf(h[i + k].y, g[k], acc.y);
            acc.z = fmaf(h[i + k].z, g[k], acc.z);
            acc.w = fmaf(h[i + k].w, g[k], acc.w);
        }
        // write-once 256 MB stream: keep it out of L2 (entries/cnt stay hot).
        // clang's builtin needs a native vector type, not HIP_vector_type.
        f32x4 av; av.x = acc.x; av.y = acc.y; av.z = acc.z; av.w = acc.w;
        __builtin_nontemporal_store(av, (f32x4*)(dst + ((size_t)i << 10)));
    }
}

extern "C" void kernel_launch(void* const* d_in, const int* in_sizes, int n_in,
                              void* d_out, int out_size, void* d_ws, size_t ws_size,
                              hipStream_t stream)
{
    const float2* pos      = (const float2*)d_in[0];
    const float*  vel_chan = (const float*)d_in[1];
    const float*  flux     = (const float*)d_in[2];
    const float*  vel_axis = (const float*)d_in[3];
    const float*  k2d      = (const float*)d_in[4];
    float* out = (float*)d_out;

    unsigned* cnt     = (unsigned*)d_ws;                       // 64 KB
    uint2*    entries = (uint2*)((char*)d_ws + (1 << 20));     // ~42 MB

    const int M = in_sizes[1];  // 1,600,000 points

    hipMemsetAsync(cnt, 0, NBINS * sizeof(unsigned), stream);

    splat_bin<<<(M + 255) / 256, 256, 0, stream>>>(
        pos, vel_chan, flux, vel_axis, cnt, entries, M);

    conv_tile<<<dim3(NT * NT, NV), 256, 0, stream>>>(cnt, entries, k2d, out);
}

// Round 6
// 414.065 us; speedup vs baseline: 1.0918x; 1.0918x over previous
//
#include <hip/hip_runtime.h>
#include <math.h>

#define N_PIX 1024
#define NV 64
#define NT 16                 // tiles per axis (1024/64)
#define TILE 64
#define HALO 70               // TILE + 6 (7x7 conv halo)
#define SHARDS 8              // one bin-space copy per XCD (blockIdx & 7 ~ XCD id)
#define CAP_S 64              // entries per (bin,shard); mean ~14.6, Poisson-safe
#define NBINS (NV * NT * NT)  // 16384 logical bins
#define CUBE_ELEMS (NV * N_PIX * N_PIX)
#define RS 72                 // raw LDS tile row stride (floats)
#define HS 68                 // h-filtered LDS tile row stride (floats)

// ---------------- pass A: bin points into XCD-sharded (channel, tile) buckets ----------------
// Index math bit-matches the XLA-jitted reference (verified): x/y via
// (c+51.15f)*10.0f, v via true fp32 division; drop on the FLAT index only
// (negative ix0/iy0 wrap into neighboring rows/channels via unflatten).
// Sharding: shard = blockIdx.x & 7 ~ the XCD this block runs on, so each XCD
// appends to its private copy of the bins -> bin tail cache lines are dirtied
// by ONE L2 only (no 8-way false sharing), and counter contention drops 8x.
__global__ __launch_bounds__(256) void splat_bin(
    const float2* __restrict__ pos,
    const float*  __restrict__ vel_chan,
    const float*  __restrict__ flux,
    const float*  __restrict__ vel_axis,
    unsigned*     __restrict__ cnt,
    uint2*        __restrict__ entries, int M)
{
    int i = blockIdx.x * 256 + threadIdx.x;
    if (i >= M) return;
    const int shard_base = (blockIdx.x & (SHARDS - 1)) * NBINS;

    const float FOV_HALF = 51.15f;
    const float INV_PIX  = 10.0f;
    const float vel0 = vel_axis[0];
    const float dv   = vel_axis[1] - vel0;

    float2 p = pos[i];
    float  v = vel_chan[i];
    float  f = flux[i];

    int ix0 = (int)floorf((p.x + FOV_HALF) * INV_PIX);
    int iy0 = (int)floorf((p.y + FOV_HALF) * INV_PIX);
    int iv0 = (int)floorf((v - vel0) / dv);

    const int margin = 4;
    if (!(ix0 >= -margin && ix0 < N_PIX + margin &&
          iy0 >= -margin && iy0 < N_PIX + margin &&
          iv0 >= 0 && iv0 < NV)) return;

    int idx = (iv0 * N_PIX + iy0) * N_PIX + ix0;   // may be negative / OOB
    if (idx < 0 || idx >= CUBE_ELEMS) return;       // reference mode="drop"
    int iv = idx >> 20;
    int iy = (idx >> 10) & 1023;
    int ix = idx & 1023;

    int tx = ix >> 6, ty = iy >> 6;
    int fx = ix & 63, fy = iy & 63;

    #pragma unroll
    for (int dy = -1; dy <= 1; ++dy) {
        if (dy < 0 && (fy >= 3 || ty == 0)) continue;      // halo of tile above
        if (dy > 0 && (fy < 61 || ty == NT - 1)) continue; // halo of tile below
        int ly  = fy + 3 - 64 * dy;                        // 0..69 within halo tile
        int byb = (iv * NT + (ty + dy)) * NT;
        #pragma unroll
        for (int dx = -1; dx <= 1; ++dx) {
            if (dx < 0 && (fx >= 3 || tx == 0)) continue;
            if (dx > 0 && (fx < 61 || tx == NT - 1)) continue;
            int lx  = fx + 3 - 64 * dx;
            int sbin = shard_base + byb + tx + dx;
            unsigned pos_ = atomicAdd(&cnt[sbin], 1u);
            if (pos_ < CAP_S)
                entries[((size_t)sbin << 6) + pos_] =
                    make_uint2((unsigned)((ly << 7) | lx), __float_as_uint(f));
        }
    }
}

// ---------------- pass B: per-tile LDS rasterize + separable 7x7 conv ----------------
// R3-proven two-pass structure (h-pass shared via LDS, computed once).
// Only change: entries come from 8 shards, consumed concurrently by eight
// 32-thread groups (no barrier needed between shards — all LDS atomics).
__global__ __launch_bounds__(256) void conv_tile(
    const unsigned* __restrict__ cnt,
    const uint2*    __restrict__ entries,
    const float*    __restrict__ k2d,
    float*          __restrict__ out)
{
    __shared__ float raw[HALO * RS];  // 70x72 = 20160 B
    __shared__ float hb [HALO * HS];  // 70x68 = 19040 B

    const int t   = threadIdx.x;
    const int ch  = blockIdx.y;
    const int bin = ch * (NT * NT) + blockIdx.x;   // blockIdx.x = ty*16+tx

    // Recover 1-D kernel from row 3 of k2d: k2d[3][j] = g3*g[j], k2d[3][3]=g3^2.
    float g[7];
    {
        float g3 = sqrtf(k2d[24]);
        #pragma unroll
        for (int j = 0; j < 7; ++j) g[j] = k2d[21 + j] / g3;
    }

    // zero the raw halo tile (5040 floats = 1260 float4)
    for (int i4 = t; i4 < HALO * RS / 4; i4 += 256)
        ((float4*)raw)[i4] = make_float4(0.f, 0.f, 0.f, 0.f);
    __syncthreads();

    // splat this bin's entries: thread group (t>>5) handles shard (t>>5).
    {
        const int sh = t >> 5, ln = t & 31;
        int sbin = sh * NBINS + bin;
        unsigned n = cnt[sbin];
        if (n > CAP_S) n = CAP_S;
        const uint2* e = entries + ((size_t)sbin << 6);
        for (unsigned i = ln; i < n; i += 32) {
            uint2 u = e[i];
            atomicAdd(&raw[(u.x >> 7) * RS + (u.x & 127)], __uint_as_float(u.y));
        }
    }
    __syncthreads();

    // horizontal: hb[r][x] = sum_j raw[r][x+j] * g[j], r in [0,70), x in [0,64)
    for (int p = t; p < HALO * 16; p += 256) {
        int r  = p >> 4;
        int xg = (p & 15) << 2;
        const float* rp = &raw[r * RS + xg];
        float4 a = *(const float4*)(rp);
        float4 b = *(const float4*)(rp + 4);
        float4 c = *(const float4*)(rp + 8);
        float rr[12] = {a.x, a.y, a.z, a.w, b.x, b.y, b.z, b.w, c.x, c.y, c.z, c.w};
        float s0 = 0.f, s1 = 0.f, s2 = 0.f, s3 = 0.f;
        #pragma unroll
        for (int j = 0; j < 7; ++j) {
            s0 = fmaf(rr[j],     g[j], s0);
            s1 = fmaf(rr[j + 1], g[j], s1);
            s2 = fmaf(rr[j + 2], g[j], s2);
            s3 = fmaf(rr[j + 3], g[j], s3);
        }
        *(float4*)&hb[r * HS + xg] = make_float4(s0, s1, s2, s3);
    }
    __syncthreads();

    // vertical + store: thread owns 4 cols x 4 rows; rolling 7-row window.
    const int xg   = (t & 15) << 2;
    const int rblk = t >> 4;          // 0..15
    const int q0   = rblk * 4;

    float4 w[8];
    #pragma unroll
    for (int j = 0; j < 6; ++j)
        w[j] = *(const float4*)&hb[(q0 + j) * HS + xg];

    const int ty = blockIdx.x >> 4, tx = blockIdx.x & 15;
    float* __restrict__ dst = out + ((size_t)ch << 20);
    const int row0 = ty * TILE + q0;
    const int colb = tx * TILE + xg;

    #pragma unroll
    for (int i = 0; i < 4; ++i) {
        w[(i + 6) & 7] = *(const float4*)&hb[(q0 + i + 6) * HS + xg];
        float4 acc = make_float4(0.f, 0.f, 0.f, 0.f);
        #pragma unroll
        for (int k = 0; k < 7; ++k) {
            float4 h4 = w[(i + k) & 7];
            acc.x = fmaf(h4.x, g[k], acc.x);
            acc.y = fmaf(h4.y, g[k], acc.y);
            acc.z = fmaf(h4.z, g[k], acc.z);
            acc.w = fmaf(h4.w, g[k], acc.w);
        }
        *(float4*)(dst + ((size_t)(row0 + i) << 10) + colb) = acc;
    }
}

extern "C" void kernel_launch(void* const* d_in, const int* in_sizes, int n_in,
                              void* d_out, int out_size, void* d_ws, size_t ws_size,
                              hipStream_t stream)
{
    const float2* pos      = (const float2*)d_in[0];
    const float*  vel_chan = (const float*)d_in[1];
    const float*  flux     = (const float*)d_in[2];
    const float*  vel_axis = (const float*)d_in[3];
    const float*  k2d      = (const float*)d_in[4];
    float* out = (float*)d_out;

    unsigned* cnt     = (unsigned*)d_ws;                       // 8*16384*4 = 512 KB
    uint2*    entries = (uint2*)((char*)d_ws + (1 << 20));     // 8*16384*64*8 = 67 MB

    const int M = in_sizes[1];  // 1,600,000 points

    hipMemsetAsync(cnt, 0, SHARDS * NBINS * sizeof(unsigned), stream);

    splat_bin<<<(M + 255) / 256, 256, 0, stream>>>(
        pos, vel_chan, flux, vel_axis, cnt, entries, M);

    conv_tile<<<dim3(NT * NT, NV), 256, 0, stream>>>(cnt, entries, k2d, out);
}